// Round 16
// baseline (27.999 us; speedup 1.0000x reference)
//
#include <hip/hip_runtime.h>

// eTofts model: B=8, T=60, H=W=256.
//   params[B,3,H,W], Cp[B,T], S0[B,1,H,W], T1[B,1,H,W] -> St[B,T,H,W] fp32
//
// Session state:
//  - R14 diagnostic: VALUBusy 80% => compute-bound. R15 (bare v_exp_f32 /
//    v_rcp_f32 + fused algebra: 5 fma + exp + rcp per element) -> 27.6 us,
//    4.93 TB/s effective vs 5.65 TB/s measured incompressible-write ceiling.
//  - R16: last lever = occupancy 8->16 waves/CU to hide the dependent
//    quarter-rate exp/rcp chain and overlap store issue. CHUNKS=2: 1024
//    blocks, 30 frames/thread; 2nd input read is L3-hot, replay is 30
//    cheap fma steps. All else unchanged (nt stores, 1 KB runs, scalar Cp).

#define N_TIME 60
#define HW (256 * 256)
#define TPB 256
#define CHUNKS 2
#define CHUNK_LEN (N_TIME / CHUNKS)  // 30
#define GRID 1024                    // 4 blocks/CU -> 16 waves/CU

typedef float f32x4 __attribute__((ext_vector_type(4)));

__device__ __forceinline__ float fexp2(float x) {
    float r;
    asm("v_exp_f32 %0, %1" : "=v"(r) : "v"(x));
    return r;
}
__device__ __forceinline__ float frcp(float x) {
    float r;
    asm("v_rcp_f32 %0, %1" : "=v"(r) : "v"(x));
    return r;
}

__global__ __launch_bounds__(TPB) void etofts_kernel(
    const float* __restrict__ params,  // [B,3,H,W]
    const float* __restrict__ Cp,      // [B,T]
    const float* __restrict__ S0,      // [B,1,H,W]
    const float* __restrict__ T1,      // [B,1,H,W]
    float* __restrict__ out)           // [B,T,H,W]
{
    const float DT     = 5.0f;
    const float TR     = 5.0f;
    const float EPS    = 1e-8f;
    const float COS_FA = 0.9848077530122081f;            // cos(10 deg)
    const float LOG2E  = 1.4426950408889634f;
    const float QC2    = 0.0225f * LOG2E;                // (R1*TR/1000)*log2e

    // 1024 blocks = 8 batches x 2 chunks x 64 tiles. Block-uniform splits
    // -> Cp loads are scalar s_load.
    const int bx    = blockIdx.x;
    const int b     = bx >> 7;
    const int chunk = (bx >> 6) & 1;
    const int blk   = bx & 63;

    // Wave w writes one 1 KB contiguous span per frame.
    const int w    = threadIdx.x >> 6;
    const int lane = threadIdx.x & 63;
    const int pixw = blk * 1024 + w * 256 + lane * 4;

    const size_t plane = (size_t)b * HW + pixw;

    const float4 kt4 = *reinterpret_cast<const float4*>(params + ((size_t)b * 3 + 0) * HW + pixw);
    const float4 vp4 = *reinterpret_cast<const float4*>(params + ((size_t)b * 3 + 1) * HW + pixw);
    const float4 ve4 = *reinterpret_cast<const float4*>(params + ((size_t)b * 3 + 2) * HW + pixw);
    const float4 s04 = *reinterpret_cast<const float4*>(S0 + plane);
    const float4 t14 = *reinterpret_cast<const float4*>(T1 + plane);

    // Loop math per element:
    //  Ce  = fma(Ce, decay, cp*DT)
    //  E   = fma(G, Ce, fma(nQv, cp, F));  u = exp2(E)
    //  den = fma(nd1, u, d0);  St = fma(Bc, rcp(den), A)
    float decay[4], G[4], nQv[4], F[4], d0[4], nd1[4], A[4], Bc[4], Ce[4];
    {
        const float ktv[4] = {kt4.x, kt4.y, kt4.z, kt4.w};
        const float vpv[4] = {vp4.x, vp4.y, vp4.z, vp4.w};
        const float vev[4] = {ve4.x, ve4.y, ve4.z, ve4.w};
        const float s0v[4] = {s04.x, s04.y, s04.z, s04.w};
        const float t1v[4] = {t14.x, t14.y, t14.z, t14.w};
#pragma unroll
        for (int i = 0; i < 4; ++i) {
            const float Ktrans = ktv[i] * (1.0f / 60.0f);
            const float Kep    = __fdividef(Ktrans, vev[i] + EPS);
            decay[i] = __expf(-Kep * DT);
            const float P  = __fdividef(TR, t1v[i] + EPS);
            const float eP = __expf(-P);
            G[i]   = -QC2 * Ktrans;
            nQv[i] = -QC2 * vpv[i];
            F[i]   = -P * LOG2E;
            const float Kc   = (1.0f - COS_FA * eP) * s0v[i];
            const float den1 = 1.0f - eP;
            const float dd0  = den1 + EPS;
            const float dd1  = COS_FA * den1;
            d0[i]  = dd0;
            nd1[i] = -dd1;
            A[i]   = Kc / dd1;
            Bc[i]  = Kc * (dd1 - dd0) / dd1;
            Ce[i]  = 0.0f;
        }
    }

    const float* cp_row = Cp + b * N_TIME;   // uniform -> scalar s_load
    const int t0 = chunk * CHUNK_LEN;

    // Replay the fma-only recurrence to this chunk's start (30 cheap steps).
    for (int t = 0; t < t0; ++t) {
        const float cpdt = cp_row[t] * DT;
#pragma unroll
        for (int i = 0; i < 4; ++i) Ce[i] = __builtin_fmaf(Ce[i], decay[i], cpdt);
    }

    float* outp = out + ((size_t)(b * N_TIME + t0)) * HW + pixw;

#pragma unroll 5
    for (int k = 0; k < CHUNK_LEN; ++k) {
        const float cp   = cp_row[t0 + k];
        const float cpdt = cp * DT;
        float st[4];
#pragma unroll
        for (int i = 0; i < 4; ++i) {
            Ce[i] = __builtin_fmaf(Ce[i], decay[i], cpdt);
            const float E   = __builtin_fmaf(G[i], Ce[i],
                              __builtin_fmaf(nQv[i], cp, F[i]));
            const float u   = fexp2(E);
            const float den = __builtin_fmaf(nd1[i], u, d0[i]);
            st[i] = __builtin_fmaf(Bc[i], frcp(den), A[i]);
        }
        f32x4 v = {st[0], st[1], st[2], st[3]};
        __builtin_nontemporal_store(v, reinterpret_cast<f32x4*>(outp + (size_t)k * HW));
    }
}

extern "C" void kernel_launch(void* const* d_in, const int* in_sizes, int n_in,
                              void* d_out, int out_size, void* d_ws, size_t ws_size,
                              hipStream_t stream) {
    const float* params = (const float*)d_in[0];
    const float* Cp     = (const float*)d_in[1];
    const float* S0     = (const float*)d_in[2];
    const float* T1     = (const float*)d_in[3];
    float* out          = (float*)d_out;

    etofts_kernel<<<GRID, TPB, 0, stream>>>(params, Cp, S0, T1, out);
}

// Round 17
// 27.339 us; speedup vs baseline: 1.0241x; 1.0241x over previous
//
#include <hip/hip_runtime.h>

// eTofts model: B=8, T=60, H=W=256.  FINAL (session-best, R15 reversion).
//   params[B,3,H,W], Cp[B,T], S0[B,1,H,W], T1[B,1,H,W] -> St[B,T,H,W] fp32
//
// Session conclusions (16 rounds):
//  - R9 probe: incompressible pure-write ceiling = 5.65 TB/s (fill kernel's
//    7.09 TB/s is a constant-data artifact; FETCH~0 => no RFO on gfx950).
//  - R14 diagnostic: pre-fusion kernel was VALUBusy 80% => compute-bound.
//  - R15: bare v_exp_f32/v_rcp_f32 + algebraic fusion (5 fma + exp + rcp
//    per element, the irreducible math) -> 27.6 us = 4.93 TB/s effective
//    = 87% of the measured pure-write ceiling, with reads+dependent math.
//  - Occupancy ladder fully mapped: 4/8/16/32 waves/CU -> 33.5/27.6/28.0/~33.
//    8 waves/CU (this config) is the optimum. R16 (16 w/CU) neutral =>
//    mixed-stream memory floor reached. ROOFLINE.
//
// Geometry: 512 blocks x 256 thr x 4 px; wave-contiguous 1 KB nt stores;
// block-uniform batch index -> Cp via scalar s_load; inputs read once.

#define N_TIME 60
#define HW (256 * 256)
#define TPB 256
#define GRID 512                     // 2 blocks/CU -> 8 waves/CU

typedef float f32x4 __attribute__((ext_vector_type(4)));

__device__ __forceinline__ float fexp2(float x) {
    float r;
    asm("v_exp_f32 %0, %1" : "=v"(r) : "v"(x));
    return r;
}
__device__ __forceinline__ float frcp(float x) {
    float r;
    asm("v_rcp_f32 %0, %1" : "=v"(r) : "v"(x));
    return r;
}

__global__ __launch_bounds__(TPB) void etofts_kernel(
    const float* __restrict__ params,  // [B,3,H,W]
    const float* __restrict__ Cp,      // [B,T]
    const float* __restrict__ S0,      // [B,1,H,W]
    const float* __restrict__ T1,      // [B,1,H,W]
    float* __restrict__ out)           // [B,T,H,W]
{
    const float DT     = 5.0f;
    const float TR     = 5.0f;
    const float EPS    = 1e-8f;
    const float COS_FA = 0.9848077530122081f;            // cos(10 deg)
    const float LOG2E  = 1.4426950408889634f;
    const float QC2    = 0.0225f * LOG2E;                // (R1*TR/1000)*log2e

    // 512 blocks: 64 per batch. Block-uniform -> Cp is scalar s_load.
    const int bx  = blockIdx.x;
    const int b   = bx >> 6;
    const int blk = bx & 63;

    // Wave w writes one 1 KB contiguous span per frame.
    const int w    = threadIdx.x >> 6;
    const int lane = threadIdx.x & 63;
    const int pixw = blk * 1024 + w * 256 + lane * 4;

    const size_t plane = (size_t)b * HW + pixw;

    const float4 kt4 = *reinterpret_cast<const float4*>(params + ((size_t)b * 3 + 0) * HW + pixw);
    const float4 vp4 = *reinterpret_cast<const float4*>(params + ((size_t)b * 3 + 1) * HW + pixw);
    const float4 ve4 = *reinterpret_cast<const float4*>(params + ((size_t)b * 3 + 2) * HW + pixw);
    const float4 s04 = *reinterpret_cast<const float4*>(S0 + plane);
    const float4 t14 = *reinterpret_cast<const float4*>(T1 + plane);

    // Loop math per element:
    //  Ce  = fma(Ce, decay, cp*DT)
    //  E   = fma(G, Ce, fma(nQv, cp, F));  u = exp2(E)
    //  den = fma(nd1, u, d0);  St = fma(Bc, rcp(den), A)
    float decay[4], G[4], nQv[4], F[4], d0[4], nd1[4], A[4], Bc[4], Ce[4];
    {
        const float ktv[4] = {kt4.x, kt4.y, kt4.z, kt4.w};
        const float vpv[4] = {vp4.x, vp4.y, vp4.z, vp4.w};
        const float vev[4] = {ve4.x, ve4.y, ve4.z, ve4.w};
        const float s0v[4] = {s04.x, s04.y, s04.z, s04.w};
        const float t1v[4] = {t14.x, t14.y, t14.z, t14.w};
#pragma unroll
        for (int i = 0; i < 4; ++i) {
            const float Ktrans = ktv[i] * (1.0f / 60.0f);
            const float Kep    = __fdividef(Ktrans, vev[i] + EPS);
            decay[i] = __expf(-Kep * DT);
            const float P  = __fdividef(TR, t1v[i] + EPS);
            const float eP = __expf(-P);
            G[i]   = -QC2 * Ktrans;
            nQv[i] = -QC2 * vpv[i];
            F[i]   = -P * LOG2E;
            const float Kc   = (1.0f - COS_FA * eP) * s0v[i];
            const float den1 = 1.0f - eP;
            const float dd0  = den1 + EPS;
            const float dd1  = COS_FA * den1;
            d0[i]  = dd0;
            nd1[i] = -dd1;
            A[i]   = Kc / dd1;
            Bc[i]  = Kc * (dd1 - dd0) / dd1;
            Ce[i]  = 0.0f;
        }
    }

    const float* cp_row = Cp + b * N_TIME;   // uniform -> scalar s_load
    float* outp = out + ((size_t)b * N_TIME) * HW + pixw;

#pragma unroll 4
    for (int t = 0; t < N_TIME; ++t) {
        const float cp   = cp_row[t];
        const float cpdt = cp * DT;
        float st[4];
#pragma unroll
        for (int i = 0; i < 4; ++i) {
            Ce[i] = __builtin_fmaf(Ce[i], decay[i], cpdt);
            const float E   = __builtin_fmaf(G[i], Ce[i],
                              __builtin_fmaf(nQv[i], cp, F[i]));
            const float u   = fexp2(E);
            const float den = __builtin_fmaf(nd1[i], u, d0[i]);
            st[i] = __builtin_fmaf(Bc[i], frcp(den), A[i]);
        }
        f32x4 v = {st[0], st[1], st[2], st[3]};
        __builtin_nontemporal_store(v, reinterpret_cast<f32x4*>(outp + (size_t)t * HW));
    }
}

extern "C" void kernel_launch(void* const* d_in, const int* in_sizes, int n_in,
                              void* d_out, int out_size, void* d_ws, size_t ws_size,
                              hipStream_t stream) {
    const float* params = (const float*)d_in[0];
    const float* Cp     = (const float*)d_in[1];
    const float* S0     = (const float*)d_in[2];
    const float* T1     = (const float*)d_in[3];
    float* out          = (float*)d_out;

    etofts_kernel<<<GRID, TPB, 0, stream>>>(params, Cp, S0, T1, out);
}